// Round 9
// baseline (27.275 us; speedup 1.0000x reference)
//
#include <hip/hip_runtime.h>

// Problem constants (fixed by setup_inputs):
//   x: (64,1,8,8) f32 = 16 KB TOTAL; KH=KW=5 -> oh=ow=4
//   rows n = b*16 + s, s = oy*4+ox, N = 1024; feat[n,k] = x[b*64+(oy+i)*8+(ox+j)], k=i*5+j
//   idx0:(128,36,6) in [0,25), lut0:(128,36,64)
//   idx1:(128, 6,6) in [0,36), lut1:(128, 6,64)
//   idx2:(128, 1,6) in [0, 6), lut2:(128, 1,64)
//   out[b,t,oy,ox] = b*2048 + t*16 + s
#define T_TREES 128
#define M0 36
#define M1 6
#define NNODES 43
// Odd image stride in LDS: gather images sweep all residues mod 8 -> ~2
// lanes/bank (free). Even stride would 4-way-conflict.
#define XPAD 67

typedef float v2f __attribute__((ext_vector_type(2)));

__device__ __forceinline__ float sigmoidf(float v) {
    return 1.f / (1.f + __expf(-v));
}

// Pair-weight in FMA-lean form: {(1-a)(1-b),(1-a)b,a(1-b),ab} per 2-row lane.
__device__ __forceinline__ void pair_w(v2f a, v2f b, v2f w[4]) {
    v2f ab = a * b;
    w[3] = ab;
    w[2] = a - ab;
    w[1] = b - ab;
    w[0] = (1.f - a) - w[1];
}

// Trilinear-factorized contraction over a 2-row pair; P scalar regs (row-inv).
__device__ __forceinline__ v2f lut_node_v2(const float* __restrict__ P,
                                           v2f a, v2f b, v2f c,
                                           v2f d, v2f e, v2f f) {
    v2f wa[4], wb[4], wc[4];
    pair_w(a, b, wa);
    pair_w(c, d, wb);
    pair_w(e, f, wc);
    v2f acc = {0.f, 0.f};
#pragma unroll
    for (int p = 0; p < 4; ++p) {
        v2f tp = {0.f, 0.f};
#pragma unroll
        for (int q = 0; q < 4; ++q) {
            const float* Pq = P + p * 16 + q * 4;
            v2f tq = Pq[0] * wc[0] + Pq[1] * wc[1] + Pq[2] * wc[2] + Pq[3] * wc[3];
            tp += tq * wb[q];
        }
        acc += tp * wa[p];
    }
    return acc;
}

// ===== Single fused kernel: block = (tree t, 256-row quarter) =====
// All 3 layers in LDS; two intra-block barriers; no workspace, no second
// dispatch, no h0 HBM round-trip. 512 blocks x 384 thr = exactly 2
// blocks/CU (71 KB LDS each), one dispatch pass, 3 waves/SIMD.
// Layer 0: wave w owns nodes 6w..6w+5 (node-stationary, P hoisted to 64
// regs per node, amortized over 2 pair-iters x 64 lanes = 256 rows).
// (384,3): VGPR cap ~170 vs ~130-reg body — cap ABOVE need (R5 lesson).
__global__ __launch_bounds__(384, 3) void fused_kernel(
    const float* __restrict__ x,
    const int* __restrict__ idx0, const float* __restrict__ lut0,
    const int* __restrict__ idx1, const float* __restrict__ lut1,
    const int* __restrict__ idx2, const float* __restrict__ lut2,
    float* __restrict__ out) {
    __shared__ float xs[64 * XPAD];                  // 17152 B (all of x, padded)
    __shared__ __align__(16) float Ps[NNODES * 64];  // 11008 B sigmoided LUTs
    __shared__ __align__(8) float h0s[M0 * 256];     // 36864 B
    __shared__ __align__(8) float h1s[M1 * 256];     //  6144 B   => 71168 B total

    const int tid = threadIdx.x;
    const int bx = blockIdx.x;          // bx = q*128 + t: all 4 quarters of a
    const int t = bx & 127;             // tree share an XCD (128 % 8 == 0)
    const int q = bx >> 7;              // row quarter [0,4)

    // ---- prologue: stage x (padded) + sigmoid(all 43 node LUTs) ----
    for (int i = tid; i < 4096; i += 384)
        xs[(i >> 6) * XPAD + (i & 63)] = x[i];
    for (int i = tid; i < NNODES * 64; i += 384) {
        float v;
        if (i < M0 * 64)              v = lut0[t * (M0 * 64) + i];
        else if (i < (M0 + M1) * 64)  v = lut1[t * (M1 * 64) + (i - M0 * 64)];
        else                          v = lut2[t * 64 + (i - (M0 + M1) * 64)];
        Ps[i] = sigmoidf(v);
    }
    __syncthreads();

    const int w = tid >> 6, ln = tid & 63;

    // ---- layer 0: wave w -> nodes 6w..6w+5 over this quarter's 256 rows ----
#pragma unroll 1
    for (int k = 0; k < 6; ++k) {
        const int m = w * 6 + k;
        float P[64];
#pragma unroll
        for (int i = 0; i < 16; ++i) {
            float4 v = reinterpret_cast<const float4*>(Ps + m * 64)[i];
            P[4 * i] = v.x; P[4 * i + 1] = v.y; P[4 * i + 2] = v.z; P[4 * i + 3] = v.w;
        }
        const int* id = idx0 + (t * M0 + m) * 6;
        int di[6];
#pragma unroll
        for (int j = 0; j < 6; ++j) {
            int kk = id[j];
            int ii = (kk * 13) >> 6;         // kk/5 for kk in [0,25)
            di[j] = kk - 5 * ii + ii * 8;    // i*8 + j window offset
        }
#pragma unroll
        for (int u = 0; u < 2; ++u) {
            int pl = u * 64 + ln;            // local pair [0,128)
            int r = 2 * pl;                  // local (even) row
            int row = q * 256 + r;
            int b = row >> 4, s = row & 15;  // s even
            int xb = b * XPAD + (s >> 2) * 8 + (s & 3);
            v2f g[6];
#pragma unroll
            for (int j = 0; j < 6; ++j) {
                int a0 = xb + di[j];
                g[j].x = xs[a0];             // fuse -> ds_read2_b32
                g[j].y = xs[a0 + 1];
            }
            v2f rr = lut_node_v2(P, g[0], g[1], g[2], g[3], g[4], g[5]);
            *reinterpret_cast<v2f*>(h0s + m * 256 + r) = rr;
        }
    }
    __syncthreads();

    // ---- layer 1: wave w = node w (6 waves, all busy) ----
    {
        float P[64];
#pragma unroll
        for (int i = 0; i < 16; ++i) {
            float4 v = reinterpret_cast<const float4*>(Ps + (M0 + w) * 64)[i];
            P[4 * i] = v.x; P[4 * i + 1] = v.y; P[4 * i + 2] = v.z; P[4 * i + 3] = v.w;
        }
        const int* id = idx1 + (t * M1 + w) * 6;
#pragma unroll
        for (int u = 0; u < 2; ++u) {
            int pl = u * 64 + ln;
            int r = 2 * pl;
            v2f g[6];
#pragma unroll
            for (int j = 0; j < 6; ++j)
                g[j] = *reinterpret_cast<const v2f*>(h0s + id[j] * 256 + r);
            v2f rr = lut_node_v2(P, g[0], g[1], g[2], g[3], g[4], g[5]);
            *reinterpret_cast<v2f*>(h1s + w * 256 + r) = rr;
        }
    }
    __syncthreads();

    // ---- layer 2: first 2 waves, one pair per thread ----
    if (tid < 128) {
        float P[64];
#pragma unroll
        for (int i = 0; i < 16; ++i) {
            float4 v = reinterpret_cast<const float4*>(Ps + (M0 + M1) * 64)[i];
            P[4 * i] = v.x; P[4 * i + 1] = v.y; P[4 * i + 2] = v.z; P[4 * i + 3] = v.w;
        }
        const int* id = idx2 + t * 6;
        int r = 2 * tid;
        v2f g[6];
#pragma unroll
        for (int j = 0; j < 6; ++j)
            g[j] = *reinterpret_cast<const v2f*>(h1s + id[j] * 256 + r);
        v2f o = lut_node_v2(P, g[0], g[1], g[2], g[3], g[4], g[5]);
        int row = q * 256 + r;
        int b = row >> 4, s = row & 15;
        *reinterpret_cast<v2f*>(out + b * (T_TREES * 16) + t * 16 + s) = o;
    }
}

extern "C" void kernel_launch(void* const* d_in, const int* in_sizes, int n_in,
                              void* d_out, int out_size, void* d_ws, size_t ws_size,
                              hipStream_t stream) {
    const float* x    = (const float*)d_in[0];
    const int*   idx0 = (const int*)  d_in[1];
    const float* lut0 = (const float*)d_in[2];
    const int*   idx1 = (const int*)  d_in[3];
    const float* lut1 = (const float*)d_in[4];
    const int*   idx2 = (const int*)  d_in[5];
    const float* lut2 = (const float*)d_in[6];
    float* out = (float*)d_out;

    fused_kernel<<<dim3(4 * T_TREES), 384, 0, stream>>>(
        x, idx0, lut0, idx1, lut1, idx2, lut2, out);   // 512 blocks = 2/CU
}

// Round 10
// 25.419 us; speedup vs baseline: 1.0730x; 1.0730x over previous
//
#include <hip/hip_runtime.h>

// Problem constants (fixed by setup_inputs):
//   x: (64,1,8,8) f32 = 16 KB TOTAL; KH=KW=5 -> oh=ow=4
//   rows n = b*16 + s, s = oy*4+ox, N = 1024; feat[n,k] = x[b*64+(oy+i)*8+(ox+j)], k=i*5+j
//   idx0:(128,36,6) in [0,25), lut0:(128,36,64)
//   idx1:(128, 6,6) in [0,36), lut1:(128, 6,64)
//   idx2:(128, 1,6) in [0, 6), lut2:(128, 1,64)
//   out[b,t,oy,ox] = b*2048 + t*16 + s
#define T_TREES 128
#define M0 36
#define M1 6
#define NROWS 1024
#define XPAD 67   // odd LDS image stride -> gather banks sweep residues, ~2-way max (free)

typedef float v2f __attribute__((ext_vector_type(2)));

__device__ __forceinline__ float sigmoidf(float v) {
    return 1.f / (1.f + __expf(-v));
}

// Force a wave-uniform value into an SGPR (readfirstlane).
__device__ __forceinline__ float rflf(float v) {
    return __builtin_bit_cast(float, __builtin_amdgcn_readfirstlane(__builtin_bit_cast(int, v)));
}
__device__ __forceinline__ int rfli(int v) {
    return __builtin_amdgcn_readfirstlane(v);
}

// Pair-weight, FMA-lean: {(1-a)(1-b),(1-a)b,a(1-b),ab} per 2-row lane.
__device__ __forceinline__ void pair_w(v2f a, v2f b, v2f w[4]) {
    v2f ab = a * b;
    w[3] = ab;
    w[2] = a - ab;
    w[1] = b - ab;
    w[0] = (1.f - a) - w[1];
}

// Trilinear contraction over a row-pair. P elements are SGPR-resident scalars
// (each v_pk_fma reads 1 SGPR + vector operands -> near-zero VGPR cost).
__device__ __forceinline__ v2f lut_node_v2(const float* __restrict__ P,
                                           v2f a, v2f b, v2f c,
                                           v2f d, v2f e, v2f f) {
    v2f wa[4], wb[4], wc[4];
    pair_w(a, b, wa);
    pair_w(c, d, wb);
    pair_w(e, f, wc);
    v2f acc = {0.f, 0.f};
#pragma unroll
    for (int p = 0; p < 4; ++p) {
        v2f tp = {0.f, 0.f};
#pragma unroll
        for (int q = 0; q < 4; ++q) {
            const float* Pq = P + p * 16 + q * 4;
            v2f tq = Pq[0] * wc[0] + Pq[1] * wc[1] + Pq[2] * wc[2] + Pq[3] * wc[3];
            tp += tq * wb[q];
        }
        acc += tp * wa[p];
    }
    return acc;
}

// ===== layer 0: wave-stationary node, row-pair per lane, P in SGPRs =====
// Wave w owns node (t, mg*4+w) for all 1024 rows (8 pair-iters). P values are
// readfirstlane'd once per node -> SGPR file, so VGPR count stays ~64-80 and
// all 4.5 waves/SIMD of the grid are co-resident (vs ~2-3 with P in VGPRs,
// which left VALUBusy at ~30% in R1-R3 profiles).
__global__ __launch_bounds__(256) void l0_kernel(
    const float* __restrict__ x, const int* __restrict__ idx0,
    const float* __restrict__ lut0, float* __restrict__ h0) {
    __shared__ float xs[64 * XPAD];          // 17152 B
    __shared__ __align__(16) float Ps[4 * 64];

    const int tid = threadIdx.x;
    const int bx = blockIdx.x;               // bx = mg*128 + t (t fast -> XCD locality)
    const int t = bx & 127;
    const int mg = bx >> 7;                  // node group [0,9)

    // stage x (coalesced float4 reads; scalar LDS writes, odd stride)
#pragma unroll
    for (int k = 0; k < 4; ++k) {
        int i4 = tid + k * 256;              // float4 index (16 per image)
        float4 v = reinterpret_cast<const float4*>(x)[i4];
        float* dst = xs + (i4 >> 4) * XPAD + (i4 & 15) * 4;
        dst[0] = v.x; dst[1] = v.y; dst[2] = v.z; dst[3] = v.w;
    }
    Ps[tid] = sigmoidf(lut0[(t * M0 + mg * 4) * 64 + tid]);  // 4 nodes x 64
    __syncthreads();

    const int wu = rfli(tid >> 6);           // provably wave-uniform wave id
    const int ln = tid & 63;
    const int m = mg * 4 + wu;               // uniform -> idx loads go scalar

    // P -> SGPRs: 16 broadcast b128 reads + 64 readfirstlanes, once per node
    float P[64];
#pragma unroll
    for (int i = 0; i < 16; ++i) {
        float4 v = reinterpret_cast<const float4*>(Ps + wu * 64)[i];
        P[4 * i + 0] = rflf(v.x);
        P[4 * i + 1] = rflf(v.y);
        P[4 * i + 2] = rflf(v.z);
        P[4 * i + 3] = rflf(v.w);
    }

    const int* id = idx0 + (t * M0 + m) * 6; // uniform address -> s_load
    int di[6];
#pragma unroll
    for (int j = 0; j < 6; ++j) {
        int k = id[j];
        int ii = (k * 13) >> 6;              // k/5 for k in [0,25)
        di[j] = k - 5 * ii + ii * 8;         // i*8 + j window offset
    }

    float* __restrict__ hout = h0 + (t * M0 + m) * NROWS;
#pragma unroll 2
    for (int u = 0; u < 8; ++u) {
        int p = u * 64 + ln;                 // pair id: rows 2p,2p+1
        int b = p >> 3;                      // image
        int s = (p & 7) * 2;                 // even position
        int xb = b * XPAD + (s >> 2) * 8 + (s & 3);
        v2f g[6];
#pragma unroll
        for (int j = 0; j < 6; ++j) {
            int a0 = xb + di[j];
            g[j].x = xs[a0];                 // fuses -> ds_read2_b32
            g[j].y = xs[a0 + 1];
        }
        v2f r = lut_node_v2(P, g[0], g[1], g[2], g[3], g[4], g[5]);
        *reinterpret_cast<v2f*>(hout + 2 * p) = r;   // global_store_dwordx2
    }
}

// ===== layers 1+2 fused: block = (t, eighth of rows), 1024 blocks x 384 thr
// (~6 waves/SIMD to hide global h0 latency). Wave w = layer-1 node w over 128
// rows (1 pair/lane), P via SGPRs; then wave 0 does layer 2 from LDS h1.
__global__ __launch_bounds__(384) void l12_kernel(
    const float* __restrict__ h0, const int* __restrict__ idx1,
    const float* __restrict__ lut1, const int* __restrict__ idx2,
    const float* __restrict__ lut2, float* __restrict__ out) {
    __shared__ __align__(16) float Ps[(M1 + 1) * 64];   // 448 floats
    __shared__ __align__(8) float h1s[M1 * 128];        // 3 KB

    const int tid = threadIdx.x;
    const int bx = blockIdx.x;               // bx = e*128 + t
    const int t = bx & 127;
    const int e = bx >> 7;                   // row eighth [0,8)

    for (int i = tid; i < (M1 + 1) * 64; i += 384) {
        float v = (i < M1 * 64) ? lut1[t * (M1 * 64) + i] : lut2[t * 64 + (i - M1 * 64)];
        Ps[i] = sigmoidf(v);
    }
    __syncthreads();

    const int wu = rfli(tid >> 6);
    const int ln = tid & 63;

    // layer 1: wave wu = node wu of tree t over rows [e*128, e*128+128)
    {
        float P[64];
#pragma unroll
        for (int i = 0; i < 16; ++i) {
            float4 v = reinterpret_cast<const float4*>(Ps + wu * 64)[i];
            P[4 * i + 0] = rflf(v.x);
            P[4 * i + 1] = rflf(v.y);
            P[4 * i + 2] = rflf(v.z);
            P[4 * i + 3] = rflf(v.w);
        }
        const int* id = idx1 + (t * M1 + wu) * 6;   // uniform -> s_load
        int rr = e * 128 + 2 * ln;                  // global even row
        v2f g[6];
#pragma unroll
        for (int j = 0; j < 6; ++j)
            g[j] = *reinterpret_cast<const v2f*>(h0 + (t * M0 + id[j]) * NROWS + rr);
        v2f r = lut_node_v2(P, g[0], g[1], g[2], g[3], g[4], g[5]);
        *reinterpret_cast<v2f*>(h1s + wu * 128 + 2 * ln) = r;
    }
    __syncthreads();

    // layer 2: wave 0, one pair per lane
    if (tid < 64) {
        float P[64];
#pragma unroll
        for (int i = 0; i < 16; ++i) {
            float4 v = reinterpret_cast<const float4*>(Ps + M1 * 64)[i];
            P[4 * i + 0] = rflf(v.x);
            P[4 * i + 1] = rflf(v.y);
            P[4 * i + 2] = rflf(v.z);
            P[4 * i + 3] = rflf(v.w);
        }
        const int* id = idx2 + t * 6;
        int rl = 2 * tid;
        v2f g[6];
#pragma unroll
        for (int j = 0; j < 6; ++j)
            g[j] = *reinterpret_cast<const v2f*>(h1s + id[j] * 128 + rl);
        v2f o = lut_node_v2(P, g[0], g[1], g[2], g[3], g[4], g[5]);
        int row = e * 128 + rl;
        int b = row >> 4, s = row & 15;
        *reinterpret_cast<v2f*>(out + b * (T_TREES * 16) + t * 16 + s) = o;
    }
}

// ===== fallback (ws too small): self-contained single kernel =====
__global__ __launch_bounds__(128) void clut_fb_kernel(
    const float* __restrict__ x,
    const int* __restrict__ idx0, const float* __restrict__ lut0,
    const int* __restrict__ idx1, const float* __restrict__ lut1,
    const int* __restrict__ idx2, const float* __restrict__ lut2,
    float* __restrict__ out) {
    __shared__ __align__(16) float slut[43 * 64];
    __shared__ float feat[25 * 128];
    __shared__ float h0[M0 * 128];
    __shared__ float h1[M1 * 128];

    const int tid = threadIdx.x;
    const int t = blockIdx.y;
    for (int i = tid; i < 43 * 64; i += 128) {
        float v;
        if (i < M0 * 64)              v = lut0[t * (M0 * 64) + i];
        else if (i < (M0 + M1) * 64)  v = lut1[t * (M1 * 64) + (i - M0 * 64)];
        else                          v = lut2[t * 64 + (i - (M0 + M1) * 64)];
        slut[i] = sigmoidf(v);
    }
    const int n = blockIdx.x * 128 + tid;
    const int b = n >> 4, s = n & 15;
    const float* xb = x + b * 64 + (s >> 2) * 8 + (s & 3);
#pragma unroll
    for (int i = 0; i < 5; ++i)
#pragma unroll
        for (int j = 0; j < 5; ++j)
            feat[(i * 5 + j) * 128 + tid] = xb[i * 8 + j];
    __syncthreads();
    for (int m = 0; m < M0; ++m) {
        const int* id = idx0 + (t * M0 + m) * 6;
        v2f g[6];
#pragma unroll
        for (int j = 0; j < 6; ++j) { g[j].x = feat[id[j] * 128 + tid]; g[j].y = 0.f; }
        v2f r = lut_node_v2(slut + m * 64, g[0], g[1], g[2], g[3], g[4], g[5]);
        h0[m * 128 + tid] = r.x;
    }
    for (int m = 0; m < M1; ++m) {
        const int* id = idx1 + (t * M1 + m) * 6;
        v2f g[6];
#pragma unroll
        for (int j = 0; j < 6; ++j) { g[j].x = h0[id[j] * 128 + tid]; g[j].y = 0.f; }
        v2f r = lut_node_v2(slut + (M0 + m) * 64, g[0], g[1], g[2], g[3], g[4], g[5]);
        h1[m * 128 + tid] = r.x;
    }
    {
        const int* id = idx2 + t * 6;
        v2f g[6];
#pragma unroll
        for (int j = 0; j < 6; ++j) { g[j].x = h1[id[j] * 128 + tid]; g[j].y = 0.f; }
        v2f r = lut_node_v2(slut + (M0 + M1) * 64, g[0], g[1], g[2], g[3], g[4], g[5]);
        out[b * (T_TREES * 16) + t * 16 + s] = r.x;
    }
}

extern "C" void kernel_launch(void* const* d_in, const int* in_sizes, int n_in,
                              void* d_out, int out_size, void* d_ws, size_t ws_size,
                              hipStream_t stream) {
    const float* x    = (const float*)d_in[0];
    const int*   idx0 = (const int*)  d_in[1];
    const float* lut0 = (const float*)d_in[2];
    const int*   idx1 = (const int*)  d_in[3];
    const float* lut1 = (const float*)d_in[4];
    const int*   idx2 = (const int*)  d_in[5];
    const float* lut2 = (const float*)d_in[6];
    float* out = (float*)d_out;

    const size_t h0_bytes = (size_t)T_TREES * M0 * NROWS * sizeof(float);  // 18.9 MB
    if (ws_size >= h0_bytes) {
        float* h0 = (float*)d_ws;
        l0_kernel<<<dim3((M0 / 4) * T_TREES), 256, 0, stream>>>(x, idx0, lut0, h0);        // 1152 blocks
        l12_kernel<<<dim3(8 * T_TREES), 384, 0, stream>>>(h0, idx1, lut1, idx2, lut2, out); // 1024 blocks
    } else {
        dim3 grid(NROWS / 128, T_TREES);
        clut_fb_kernel<<<grid, 128, 0, stream>>>(x, idx0, lut0, idx1, lut1, idx2, lut2, out);
    }
}